// Round 13
// baseline (318.632 us; speedup 1.0000x reference)
//
#include <hip/hip_runtime.h>
#include <cstddef>

#define DMODEL 512
#define HEADS  8
#define DH     64
#define CCH    512
#define BATCH  4
#define SEQ    512
#define NEDGE  4096
#define NLAYER 2
#define HC     (HEADS*CCH)

typedef unsigned short bf16_t;
typedef __attribute__((ext_vector_type(8))) short short8;
typedef __attribute__((ext_vector_type(4))) float floatx4;

__device__ __forceinline__ bf16_t f2bf(float f){
  unsigned u = __float_as_uint(f);
  unsigned r = (u + 0x7FFFu + ((u>>16)&1u)) >> 16;
  return (bf16_t)r;
}
__device__ __forceinline__ float bf2f(bf16_t u){ return __uint_as_float(((unsigned)u)<<16); }

// ---------------- fused preamble: edge bucketing + weight transpose + x convert ----------------
struct WtJob { const float* W[10]; bf16_t* WT[10]; };
// grid: blocks [0,4) = edges per batch; [4,3076) = weight transpose tiles; [3076,4100) = f2b
__global__ __launch_bounds__(256) void k_pre(const int* __restrict__ edges,
    const int* __restrict__ edge_num, int* __restrict__ cnt, int* __restrict__ offs,
    int* __restrict__ elist, float* __restrict__ attn_nodes, int an_total,
    WtJob j, const float* __restrict__ x, bf16_t* __restrict__ xbf, int n4){
  __shared__ int cnt_l[SEQ];
  __shared__ int off_l[SEQ];
  __shared__ int cur_l[SEQ];
  __shared__ float T[32][65];
  int bz = blockIdx.x, tid = threadIdx.x;
  if (bz < 4){
    int b = bz;
    int chunk = an_total / BATCH;
    for (int i = tid; i < chunk; i += 256) attn_nodes[b*chunk + i] = 0.f;
    for (int s = tid; s < SEQ; s += 256) cnt_l[s] = 0;
    __syncthreads();
    int ne = edge_num[b];
    const int* dstrow = edges + (size_t)b*2*NEDGE + NEDGE;
    for (int e = tid; e < ne; e += 256) atomicAdd(&cnt_l[dstrow[e]], 1);
    __syncthreads();
    if (tid == 0){
      int acc = 0;
      for (int s = 0; s < SEQ; s++){ off_l[s] = acc; acc += cnt_l[s]; }
    }
    __syncthreads();
    for (int s = tid; s < SEQ; s += 256) cur_l[s] = off_l[s];
    __syncthreads();
    for (int e = tid; e < ne; e += 256){
      int dst = dstrow[e];
      int pos = atomicAdd(&cur_l[dst], 1);
      elist[(size_t)b*NEDGE + pos] = e;
    }
    for (int s = tid; s < SEQ; s += 256){
      cnt[b*SEQ + s]  = cnt_l[s];
      offs[b*SEQ + s] = off_l[s];
    }
  } else if (bz < 4+3072){
    int idx = bz - 4;
    int t = idx >> 4;
    int k0 = (idx & 15)*32;
    int wsel, n0, N;
    if (t < 64){ wsel = t>>3; n0 = (t&7)*64; N = 512; }
    else { int t2 = t-64; wsel = 8 + (t2>>6); n0 = (t2&63)*64; N = 4096; }
    const float* W = j.W[wsel];
    bf16_t* WT = j.WT[wsel];
    const int K = 512;
    int lk = tid>>3, ln = (tid&7)*8;
    const float* src = W + (size_t)(k0+lk)*N + n0 + ln;
    float4 v0 = *(const float4*)src;
    float4 v1 = *(const float4*)(src+4);
    T[lk][ln+0]=v0.x; T[lk][ln+1]=v0.y; T[lk][ln+2]=v0.z; T[lk][ln+3]=v0.w;
    T[lk][ln+4]=v1.x; T[lk][ln+5]=v1.y; T[lk][ln+6]=v1.z; T[lk][ln+7]=v1.w;
    __syncthreads();
    int wn = tid>>2, wk = (tid&3)*8;
    ushort4 o0, o1;
    o0.x=f2bf(T[wk+0][wn]); o0.y=f2bf(T[wk+1][wn]); o0.z=f2bf(T[wk+2][wn]); o0.w=f2bf(T[wk+3][wn]);
    o1.x=f2bf(T[wk+4][wn]); o1.y=f2bf(T[wk+5][wn]); o1.z=f2bf(T[wk+6][wn]); o1.w=f2bf(T[wk+7][wn]);
    bf16_t* dst = WT + (size_t)(n0+wn)*K + k0 + wk;
    *(ushort4*)dst = o0;
    *(ushort4*)(dst+4) = o1;
  } else {
    int i = (bz-3076)*256 + tid;
    if (i < n4){
      float4 v = ((const float4*)x)[i];
      ushort4 o;
      o.x=f2bf(v.x); o.y=f2bf(v.y); o.z=f2bf(v.z); o.w=f2bf(v.w);
      ((ushort4*)xbf)[i]=o;
    }
  }
}

// ---------------- MFMA GEMM: 64x64 tile, BK=64, LDS dbuf, XOR-swizzled LDS ----------------
struct GemmB {
  const bf16_t* W; const float* bias; float* C; bf16_t* Cb;
  const float* att_s; const float* att_d; float* asrc; float* adst;
};
struct GemmB3 { GemmB g[3]; };

__global__ __launch_bounds__(256) void k_gemm_mfma(const bf16_t* __restrict__ A, GemmB3 p,
                                                   int N, int K){
  const GemmB& g = p.g[blockIdx.z];
  const bf16_t* Wt  = g.W;
  const float* bias = g.bias;
  float* C          = g.C;
  bf16_t* Cb        = g.Cb;
  __shared__ __align__(16) bf16_t As[2][64*64];
  __shared__ __align__(16) bf16_t Bs[2][64*64];
  int bm = blockIdx.x*64, bn = blockIdx.y*64;
  int tid = threadIdx.x;
  int wave = tid>>6, lane = tid&63;
  int wy = wave>>1, wx = wave&1;
  int quad = lane>>4, l16 = lane&15;
  int l7 = l16&7;
  floatx4 acc[2][2];
  #pragma unroll
  for (int i=0;i<2;i++)
    #pragma unroll
    for (int j=0;j<2;j++) acc[i][j] = (floatx4){0.f,0.f,0.f,0.f};
  int sr = tid>>2;
  int sch = (tid&3)*2;
  int sc = sch<<3;
  int wof0 = sr*64 + ((sch     ^ (sr&7))<<3);
  int wof1 = sr*64 + (((sch+1) ^ (sr&7))<<3);
  const bf16_t* Aptr = A  + (size_t)(bm+sr)*K + sc;
  const bf16_t* Bptr = Wt + (size_t)(bn+sr)*K + sc;
  uint4 a0, a1, b0, b1;
  a0 = *(const uint4*)(Aptr);     a1 = *(const uint4*)(Aptr + 8);
  b0 = *(const uint4*)(Bptr);     b1 = *(const uint4*)(Bptr + 8);
  *(uint4*)(As[0] + wof0) = a0;
  *(uint4*)(As[0] + wof1) = a1;
  *(uint4*)(Bs[0] + wof0) = b0;
  *(uint4*)(Bs[0] + wof1) = b1;
  int rch0 = (quad ^ l7)<<3;
  int rch1 = rch0 ^ 32;
  const int nk = K>>6;
  for (int k=0; k<nk; k++){
    __syncthreads();
    if (k+1 < nk){
      int ko = (k+1)<<6;
      a0 = *(const uint4*)(Aptr + ko);     a1 = *(const uint4*)(Aptr + ko + 8);
      b0 = *(const uint4*)(Bptr + ko);     b1 = *(const uint4*)(Bptr + ko + 8);
    }
    const bf16_t* Ab = As[k&1];
    const bf16_t* Bb = Bs[k&1];
    short8 af[2][2], bfr[2][2];
    #pragma unroll
    for (int i=0;i<2;i++){
      int ra = (wy*32+i*16+l16)*64;
      af[0][i] = *(const short8*)(Ab + ra + rch0);
      af[1][i] = *(const short8*)(Ab + ra + rch1);
    }
    #pragma unroll
    for (int j=0;j<2;j++){
      int rb = (wx*32+j*16+l16)*64;
      bfr[0][j] = *(const short8*)(Bb + rb + rch0);
      bfr[1][j] = *(const short8*)(Bb + rb + rch1);
    }
    #pragma unroll
    for (int i=0;i<2;i++)
      #pragma unroll
      for (int j=0;j<2;j++){
        acc[i][j] = __builtin_amdgcn_mfma_f32_16x16x32_bf16(af[0][i], bfr[0][j], acc[i][j], 0,0,0);
        acc[i][j] = __builtin_amdgcn_mfma_f32_16x16x32_bf16(af[1][i], bfr[1][j], acc[i][j], 0,0,0);
      }
    if (k+1 < nk){
      bf16_t* Aw = As[(k+1)&1];
      bf16_t* Bw = Bs[(k+1)&1];
      *(uint4*)(Aw + wof0) = a0;
      *(uint4*)(Aw + wof1) = a1;
      *(uint4*)(Bw + wof0) = b0;
      *(uint4*)(Bw + wof1) = b1;
    }
  }
  #pragma unroll
  for (int i=0;i<2;i++){
    int row = bm + wy*32 + i*16 + quad*4;
    #pragma unroll
    for (int j=0;j<2;j++){
      int col = bn + wx*32 + j*16 + l16;
      float bi = bias ? bias[col] : 0.f;
      #pragma unroll
      for (int r=0;r<4;r++){
        float vvv = acc[i][j][r] + bi;
        if (C)  C[(size_t)(row+r)*N + col] = vvv;
        if (Cb) Cb[(size_t)(row+r)*N + col] = f2bf(vvv);
      }
    }
  }
  if (g.asrc){
    int colbase = bn + wx*32;
    int hidx = colbase >> 9;
    float aw_s[2], aw_d[2];
    #pragma unroll
    for (int j=0;j<2;j++){
      int col = colbase + j*16 + l16;
      aw_s[j] = g.att_s[col];
      aw_d[j] = g.att_d[col];
    }
    #pragma unroll
    for (int i=0;i<2;i++){
      #pragma unroll
      for (int r=0;r<4;r++){
        float ps=0.f, pd=0.f;
        #pragma unroll
        for (int j=0;j<2;j++){ ps += acc[i][j][r]*aw_s[j]; pd += acc[i][j][r]*aw_d[j]; }
        #pragma unroll
        for (int m2=1;m2<16;m2<<=1){ ps += __shfl_xor(ps,m2); pd += __shfl_xor(pd,m2); }
        if (l16==0){
          int row = bm + wy*32 + i*16 + quad*4 + r;
          atomicAdd(&g.asrc[row*HEADS + hidx], ps);
          atomicAdd(&g.adst[row*HEADS + hidx], pd);
        }
      }
    }
  }
}

// ---------------- split-K flash MFMA attention: 32 Q-rows/block, wave pairs split keys ----------
// waves: w = rg*2 + kh; rg=rowgroup (16 rows), kh=key half (0: keys 0..255 [always valid,
// since len>=256], 1: keys 256..511 masked). Merge via LDS flash-combine.
__global__ __launch_bounds__(256) void k_attn_flash(const bf16_t* __restrict__ q,
    const bf16_t* __restrict__ k, const bf16_t* __restrict__ v,
    const int* __restrict__ input_len, bf16_t* __restrict__ o){
  __shared__ __align__(16) bf16_t Kt[2][64*72];
  __shared__ __align__(16) bf16_t Vt[2][64*72];
  __shared__ __align__(16) bf16_t Pt[4][16*72];
  __shared__ float Om[2][16*64];
  __shared__ float Ml[2][2][16];
  int q0 = blockIdx.x*32;
  int h  = blockIdx.y, b = blockIdx.z;
  int len = input_len[b];
  int tid = threadIdx.x;
  int w = tid>>6, lane = tid&63;
  int quad = lane>>4, l16 = lane&15;
  int rg = w>>1, kh = w&1;
  const bf16_t* qrow = q + ((size_t)(b*SEQ + q0 + rg*16 + l16))*DMODEL + h*DH;
  short8 qa0 = *(const short8*)(qrow + quad*8);
  short8 qa1 = *(const short8*)(qrow + quad*8 + 32);
  // staging: thread group sg stages K/V tile for key-half sg
  int sg = tid>>7;
  int st = tid & 127;
  int kr = st>>1,  kc = (st&1)*32;     // K: 2 threads/row, 32 elems each
  int vrr = st&63, vcc = (st>>6)*32;   // V: row vrr, dims vcc..vcc+31 (transposed store)
  const bf16_t* kbase = k + ((size_t)(b*SEQ))*DMODEL + h*DH;
  const bf16_t* vbase = v + ((size_t)(b*SEQ))*DMODEL + h*DH;
  floatx4 oacc[4];
  #pragma unroll
  for (int dt=0;dt<4;dt++) oacc[dt] = (floatx4){0.f,0.f,0.f,0.f};
  float mrun[4], lrun[4];
  #pragma unroll
  for (int r=0;r<4;r++){ mrun[r]=-1e30f; lrun[r]=0.f; }
  for (int t=0; t<4; t++){
    int ktg = sg*256 + t*64;
    uint4 kv[4], vv[4];
    #pragma unroll
    for (int c=0;c<4;c++) kv[c] = *(const uint4*)(kbase + (size_t)(ktg+kr)*DMODEL + kc + c*8);
    #pragma unroll
    for (int c=0;c<4;c++) vv[c] = *(const uint4*)(vbase + (size_t)(ktg+vrr)*DMODEL + vcc + c*8);
    __syncthreads();
    #pragma unroll
    for (int c=0;c<4;c++) *(uint4*)(Kt[sg] + kr*72 + kc + c*8) = kv[c];
    #pragma unroll
    for (int c=0;c<4;c++){
      const ushort* vp = (const ushort*)&vv[c];
      #pragma unroll
      for (int i2=0;i2<8;i2++) Vt[sg][(vcc + c*8 + i2)*72 + vrr] = vp[i2];
    }
    __syncthreads();
    int kabs_base = kh*256 + t*64;
    floatx4 sacc[4];
    #pragma unroll
    for (int nt=0;nt<4;nt++){
      sacc[nt] = (floatx4){0.f,0.f,0.f,0.f};
      short8 kb0 = *(const short8*)(Kt[kh] + (nt*16+l16)*72 + quad*8);
      short8 kb1 = *(const short8*)(Kt[kh] + (nt*16+l16)*72 + quad*8 + 32);
      sacc[nt] = __builtin_amdgcn_mfma_f32_16x16x32_bf16(qa0, kb0, sacc[nt], 0,0,0);
      sacc[nt] = __builtin_amdgcn_mfma_f32_16x16x32_bf16(qa1, kb1, sacc[nt], 0,0,0);
    }
    #pragma unroll
    for (int nt=0;nt<4;nt++){
      bool valid = (kabs_base + nt*16 + l16) < len;
      #pragma unroll
      for (int r=0;r<4;r++){
        float sv = sacc[nt][r]*0.125f;
        sacc[nt][r] = valid ? sv : -1e30f;
      }
    }
    float alpha[4];
    #pragma unroll
    for (int r=0;r<4;r++){
      float mx = fmaxf(fmaxf(sacc[0][r],sacc[1][r]), fmaxf(sacc[2][r],sacc[3][r]));
      #pragma unroll
      for (int off=1; off<16; off<<=1) mx = fmaxf(mx, __shfl_xor(mx, off));
      float mn = fmaxf(mrun[r], mx);
      alpha[r] = __expf(mrun[r]-mn);
      mrun[r] = mn;
      float rs = 0.f;
      #pragma unroll
      for (int nt=0;nt<4;nt++){
        float pp = __expf(sacc[nt][r]-mn);
        sacc[nt][r] = pp; rs += pp;
      }
      #pragma unroll
      for (int off=1; off<16; off<<=1) rs += __shfl_xor(rs, off);
      lrun[r] = lrun[r]*alpha[r] + rs;
    }
    #pragma unroll
    for (int dt=0;dt<4;dt++)
      #pragma unroll
      for (int r=0;r<4;r++) oacc[dt][r] *= alpha[r];
    bf16_t* pw = Pt[w];
    #pragma unroll
    for (int nt=0;nt<4;nt++)
      #pragma unroll
      for (int r=0;r<4;r++) pw[(quad*4+r)*72 + nt*16 + l16] = f2bf(sacc[nt][r]);
    short8 pa0 = *(const short8*)(pw + l16*72 + quad*8);
    short8 pa1 = *(const short8*)(pw + l16*72 + quad*8 + 32);
    #pragma unroll
    for (int dt=0;dt<4;dt++){
      short8 vb0 = *(const short8*)(Vt[kh] + (dt*16+l16)*72 + quad*8);
      short8 vb1 = *(const short8*)(Vt[kh] + (dt*16+l16)*72 + quad*8 + 32);
      oacc[dt] = __builtin_amdgcn_mfma_f32_16x16x32_bf16(pa0, vb0, oacc[dt], 0,0,0);
      oacc[dt] = __builtin_amdgcn_mfma_f32_16x16x32_bf16(pa1, vb1, oacc[dt], 0,0,0);
    }
  }
  // flash-combine the two key halves per rowgroup
  __syncthreads();
  if (kh==1){
    #pragma unroll
    for (int dt=0;dt<4;dt++)
      #pragma unroll
      for (int r=0;r<4;r++) Om[rg][(quad*4+r)*64 + dt*16 + l16] = oacc[dt][r];
    if (l16==0){
      #pragma unroll
      for (int r=0;r<4;r++){ Ml[rg][0][quad*4+r]=mrun[r]; Ml[rg][1][quad*4+r]=lrun[r]; }
    }
  }
  __syncthreads();
  if (kh==0){
    float a0[4], a1[4], invl[4];
    #pragma unroll
    for (int r=0;r<4;r++){
      float m1 = Ml[rg][0][quad*4+r];
      float l1 = Ml[rg][1][quad*4+r];
      float m  = fmaxf(mrun[r], m1);
      a0[r] = __expf(mrun[r]-m);
      a1[r] = __expf(m1-m);
      invl[r] = 1.f/(lrun[r]*a0[r] + l1*a1[r]);
    }
    bf16_t* obase = o + ((size_t)(b*SEQ + q0 + rg*16 + quad*4))*DMODEL + h*DH;
    #pragma unroll
    for (int r=0;r<4;r++)
      #pragma unroll
      for (int dt=0;dt<4;dt++){
        float val = (oacc[dt][r]*a0[r] + Om[rg][(quad*4+r)*64 + dt*16 + l16]*a1[r])*invl[r];
        obase[(size_t)r*DMODEL + dt*16 + l16] = f2bf(val);
      }
  }
}

// ---------------- fused GAT aggregation + LN + ReLU + residual + mask ----------------
__global__ __launch_bounds__(256) void k_gat_ln(const bf16_t* __restrict__ hbuf,
    const float* __restrict__ asrc, const float* __restrict__ adst,
    const int* __restrict__ offs, const int* __restrict__ cnt, const int* __restrict__ elist,
    const int* __restrict__ edges, const int* __restrict__ input_len,
    const float* __restrict__ gat_bias, const float* __restrict__ mha,
    const float* __restrict__ lng, const float* __restrict__ lnb,
    bf16_t* __restrict__ curb, float* __restrict__ outp){
  int s = blockIdx.x, b = blockIdx.y;
  int tid = threadIdx.x;
  size_t row = ((size_t)(b*SEQ+s))*DMODEL;
  int c0 = tid*2;
  float2 xv = *(const float2*)(mha + row + c0);
  if (s >= input_len[b]){
    curb[row+c0]   = f2bf(xv.x);
    curb[row+c0+1] = f2bf(xv.y);
    *(float2*)(outp + row + c0) = xv;
    return;
  }
  __shared__ float amax_s[8], den_s[8], adl[8];
  __shared__ float cf[32][8];
  __shared__ int   cs[32];
  __shared__ float red[256];
  int n = cnt[b*SEQ+s];
  const int* el = elist + (size_t)b*NEDGE + offs[b*SEQ+s];
  const int* srcrow = edges + (size_t)b*2*NEDGE;
  if (tid < 8) adl[tid] = adst[(b*SEQ+s)*HEADS + tid];
  __syncthreads();
  if (tid < 64){
    float mx[8];
    #pragma unroll
    for (int h2=0;h2<8;h2++) mx[h2] = -1e30f;
    for (int j = tid; j <= n; j += 64){
      int src = (j==n) ? s : srcrow[el[j]];
      const float* ap = asrc + (size_t)(b*SEQ+src)*HEADS;
      #pragma unroll
      for (int h2=0;h2<8;h2++){
        float a = ap[h2] + adl[h2];
        a = (a>0.f)? a : 0.2f*a;
        mx[h2] = fmaxf(mx[h2], a);
      }
    }
    #pragma unroll
    for (int h2=0;h2<8;h2++){
      float vmx = mx[h2];
      #pragma unroll
      for (int off=32; off; off>>=1) vmx = fmaxf(vmx, __shfl_xor(vmx,off,64));
      mx[h2]=vmx;
    }
    float sm[8];
    #pragma unroll
    for (int h2=0;h2<8;h2++) sm[h2]=0.f;
    for (int j = tid; j <= n; j += 64){
      int src = (j==n) ? s : srcrow[el[j]];
      const float* ap = asrc + (size_t)(b*SEQ+src)*HEADS;
      #pragma unroll
      for (int h2=0;h2<8;h2++){
        float a = ap[h2] + adl[h2];
        a = (a>0.f)? a : 0.2f*a;
        sm[h2] += __expf(a - mx[h2]);
      }
    }
    #pragma unroll
    for (int h2=0;h2<8;h2++){
      float vs = sm[h2];
      #pragma unroll
      for (int off=32; off; off>>=1) vs += __shfl_xor(vs,off,64);
      if (tid==0){ amax_s[h2]=mx[h2]; den_s[h2]=vs; }
    }
  }
  __syncthreads();
  float acc0=0.f, acc1=0.f;
  for (int j0=0; j0 <= n; j0 += 32){
    int jm = min(32, n+1-j0);
    if (tid < jm*8){
      int jj = j0 + (tid>>3), h2 = tid&7;
      int src = (jj==n) ? s : srcrow[el[jj]];
      if (h2==0) cs[tid>>3] = src;
      float a = asrc[(size_t)(b*SEQ+src)*HEADS + h2] + adl[h2];
      a = (a>0.f)? a : 0.2f*a;
      cf[tid>>3][h2] = __expf(a - amax_s[h2]) / (den_s[h2] + 1e-16f);
    }
    __syncthreads();
    for (int jj=0; jj<jm; ++jj){
      int src = cs[jj];
      const bf16_t* hrow = hbuf + ((size_t)(b*SEQ+src))*HC;
      #pragma unroll
      for (int h2=0;h2<8;h2++){
        float wgt = cf[jj][h2];
        ushort2 hv = *(const ushort2*)(hrow + h2*CCH + c0);
        acc0 += wgt * bf2f(hv.x);
        acc1 += wgt * bf2f(hv.y);
      }
    }
    __syncthreads();
  }
  float g0 = acc0*0.125f + gat_bias[c0];
  float g1 = acc1*0.125f + gat_bias[c0+1];
  red[tid] = g0+g1;
  __syncthreads();
  for (int off=128; off; off>>=1){ if (tid<off) red[tid]+=red[tid+off]; __syncthreads(); }
  float mean = red[0]*(1.f/512.f);
  __syncthreads();
  float d0 = g0-mean, d1 = g1-mean;
  red[tid] = d0*d0 + d1*d1;
  __syncthreads();
  for (int off=128; off; off>>=1){ if (tid<off) red[tid]+=red[tid+off]; __syncthreads(); }
  float inv = rsqrtf(red[0]*(1.f/512.f) + 1e-5f);
  float t0 = d0*inv*lng[c0]   + lnb[c0];
  float t1 = d1*inv*lng[c0+1] + lnb[c0+1];
  float y0 = fmaxf(t0,0.f) + xv.x;
  float y1 = fmaxf(t1,0.f) + xv.y;
  curb[row+c0]   = f2bf(y0);
  curb[row+c0+1] = f2bf(y1);
  float2 outv = { y0, y1 };
  *(float2*)(outp + row + c0) = outv;
}

extern "C" void kernel_launch(void* const* d_in, const int* in_sizes, int n_in,
                              void* d_out, int out_size, void* d_ws, size_t ws_size,
                              hipStream_t stream){
  (void)in_sizes; (void)n_in; (void)out_size; (void)ws_size;
  const float* x       = (const float*)d_in[0];
  const float* Wq      = (const float*)d_in[1];
  const float* bq      = (const float*)d_in[2];
  const float* Wk      = (const float*)d_in[3];
  const float* bk      = (const float*)d_in[4];
  const float* Wv      = (const float*)d_in[5];
  const float* bv      = (const float*)d_in[6];
  const float* Wo      = (const float*)d_in[7];
  const float* bo      = (const float*)d_in[8];
  const float* gatW    = (const float*)d_in[9];
  const float* att_src = (const float*)d_in[10];
  const float* att_dst = (const float*)d_in[11];
  const float* gat_bias= (const float*)d_in[12];
  const float* ln_g    = (const float*)d_in[13];
  const float* ln_b    = (const float*)d_in[14];
  const int* input_len  = (const int*)d_in[15];
  const int* edges      = (const int*)d_in[16];
  const int* edge_num   = (const int*)d_in[17];
  float* outp = (float*)d_out;

  char* w = (char*)d_ws;
  size_t off = 0;
  auto alloc = [&](size_t bytes)->char*{ char* p = w + off; off += (bytes + 255) & ~(size_t)255; return p; };
  const size_t BSD = (size_t)BATCH*SEQ*DMODEL;
  const size_t BSH = (size_t)BATCH*SEQ*HEADS;
  float* mha  = (float*)alloc(BSD*4);
  bf16_t* hb  = (bf16_t*)alloc((size_t)BATCH*SEQ*HC*2);
  float* attn_nodes = (float*)alloc((size_t)NLAYER*2*BSH*4);
  int* cnt    = (int*)alloc(BATCH*SEQ*4);
  int* offs   = (int*)alloc(BATCH*SEQ*4);
  int* elist  = (int*)alloc((size_t)BATCH*NEDGE*4);
  bf16_t* xbf  = (bf16_t*)alloc(BSD*2);
  bf16_t* curb = (bf16_t*)alloc(BSD*2);
  bf16_t* qbf  = (bf16_t*)alloc(BSD*2);
  bf16_t* kbf  = (bf16_t*)alloc(BSD*2);
  bf16_t* vbf  = (bf16_t*)alloc(BSD*2);
  bf16_t* obf  = (bf16_t*)alloc(BSD*2);
  bf16_t* abf  = (bf16_t*)alloc(BSD*2);
  bf16_t* wqt  = (bf16_t*)alloc((size_t)NLAYER*DMODEL*DMODEL*2);
  bf16_t* wkt  = (bf16_t*)alloc((size_t)NLAYER*DMODEL*DMODEL*2);
  bf16_t* wvt  = (bf16_t*)alloc((size_t)NLAYER*DMODEL*DMODEL*2);
  bf16_t* wot  = (bf16_t*)alloc((size_t)NLAYER*DMODEL*DMODEL*2);
  bf16_t* gwt  = (bf16_t*)alloc((size_t)NLAYER*DMODEL*HC*2);

  WtJob wj;
  for (int i=0;i<NLAYER;i++){
    size_t wo = (size_t)i*DMODEL*DMODEL;
    wj.W[i*4+0]=Wq+wo;  wj.WT[i*4+0]=wqt+wo;
    wj.W[i*4+1]=Wk+wo;  wj.WT[i*4+1]=wkt+wo;
    wj.W[i*4+2]=Wv+wo;  wj.WT[i*4+2]=wvt+wo;
    wj.W[i*4+3]=Wo+wo;  wj.WT[i*4+3]=wot+wo;
    size_t go = (size_t)i*DMODEL*HC;
    wj.W[8+i]=gatW+go;  wj.WT[8+i]=gwt+go;
  }
  // fused preamble: edges + weight transpose + x->bf16, ONE launch
  k_pre<<<dim3(4+3072+1024),256,0,stream>>>(edges, edge_num, cnt, offs, elist,
      attn_nodes, (int)(NLAYER*2*BSH), wj, x, xbf, (int)(BSD/4));

  const int M = BATCH*SEQ;
  for (int i=0;i<NLAYER;i++){
    size_t wo = (size_t)i*DMODEL*DMODEL;
    size_t bo2 = (size_t)i*DMODEL;
    float* asrc = attn_nodes + (size_t)i*2*BSH;
    float* adst = asrc + BSH;
    const bf16_t* Ab = (i==0) ? xbf : curb;
    GemmB3 qkv;
    qkv.g[0] = { wqt+wo, bq+bo2, nullptr, qbf, nullptr, nullptr, nullptr, nullptr };
    qkv.g[1] = { wkt+wo, bk+bo2, nullptr, kbf, nullptr, nullptr, nullptr, nullptr };
    qkv.g[2] = { wvt+wo, bv+bo2, nullptr, vbf, nullptr, nullptr, nullptr, nullptr };
    k_gemm_mfma<<<dim3(M/64, DMODEL/64, 3),256,0,stream>>>(Ab, qkv, DMODEL, DMODEL);
    k_attn_flash<<<dim3(SEQ/32, HEADS, BATCH),256,0,stream>>>(qbf, kbf, vbf, input_len, obf);
    GemmB3 og;
    og.g[0] = { wot+wo, bo+bo2, mha, abf, nullptr, nullptr, nullptr, nullptr };
    og.g[1] = og.g[0]; og.g[2] = og.g[0];
    k_gemm_mfma<<<dim3(M/64, DMODEL/64, 1),256,0,stream>>>(obf, og, DMODEL, DMODEL);
    GemmB3 gg;
    gg.g[0] = { gwt + (size_t)i*DMODEL*HC, nullptr, nullptr, hb,
                att_src + (size_t)i*HC, att_dst + (size_t)i*HC, asrc, adst };
    gg.g[1] = gg.g[0]; gg.g[2] = gg.g[0];
    k_gemm_mfma<<<dim3(M/64, HC/64, 1),256,0,stream>>>(abf, gg, HC, DMODEL);
    k_gat_ln<<<dim3(SEQ, BATCH),256,0,stream>>>(hb, asrc, adst, offs, cnt, elist, edges,
        input_len, gat_bias + (size_t)i*CCH, mha, ln_g+bo2, ln_b+bo2,
        curb, outp + (size_t)i*BSD);
  }
}

// Round 14
// 307.381 us; speedup vs baseline: 1.0366x; 1.0366x over previous
//
#include <hip/hip_runtime.h>
#include <cstddef>

#define DMODEL 512
#define HEADS  8
#define DH     64
#define CCH    512
#define BATCH  4
#define SEQ    512
#define NEDGE  4096
#define NLAYER 2
#define HC     (HEADS*CCH)

typedef unsigned short bf16_t;
typedef __attribute__((ext_vector_type(8))) short short8;
typedef __attribute__((ext_vector_type(4))) float floatx4;

__device__ __forceinline__ bf16_t f2bf(float f){
  unsigned u = __float_as_uint(f);
  unsigned r = (u + 0x7FFFu + ((u>>16)&1u)) >> 16;
  return (bf16_t)r;
}
__device__ __forceinline__ float bf2f(bf16_t u){ return __uint_as_float(((unsigned)u)<<16); }

// ---------------- f32 -> bf16 convert ----------------
__global__ void k_f2b(const float* __restrict__ in, bf16_t* __restrict__ out, int n4){
  int i = blockIdx.x*256 + threadIdx.x;
  if (i < n4){
    float4 v = ((const float4*)in)[i];
    ushort4 o;
    o.x=f2bf(v.x); o.y=f2bf(v.y); o.z=f2bf(v.z); o.w=f2bf(v.w);
    ((ushort4*)out)[i]=o;
  }
}

// ---------------- fused edge bucketing + accumulator zeroing ----------------
__global__ __launch_bounds__(256) void k_edges(const int* __restrict__ edges,
    const int* __restrict__ edge_num, int* __restrict__ cnt, int* __restrict__ offs,
    int* __restrict__ elist, float* __restrict__ attn_nodes, int an_total){
  __shared__ int cnt_l[SEQ];
  __shared__ int off_l[SEQ];
  __shared__ int cur_l[SEQ];
  int b = blockIdx.x, tid = threadIdx.x;
  int chunk = an_total / BATCH;
  for (int i = tid; i < chunk; i += 256) attn_nodes[b*chunk + i] = 0.f;
  for (int s = tid; s < SEQ; s += 256) cnt_l[s] = 0;
  __syncthreads();
  int ne = edge_num[b];
  const int* dstrow = edges + (size_t)b*2*NEDGE + NEDGE;
  for (int e = tid; e < ne; e += 256) atomicAdd(&cnt_l[dstrow[e]], 1);
  __syncthreads();
  if (tid == 0){
    int acc = 0;
    for (int s = 0; s < SEQ; s++){ off_l[s] = acc; acc += cnt_l[s]; }
  }
  __syncthreads();
  for (int s = tid; s < SEQ; s += 256) cur_l[s] = off_l[s];
  __syncthreads();
  for (int e = tid; e < ne; e += 256){
    int dst = dstrow[e];
    int pos = atomicAdd(&cur_l[dst], 1);
    elist[(size_t)b*NEDGE + pos] = e;
  }
  for (int s = tid; s < SEQ; s += 256){
    cnt[b*SEQ + s]  = cnt_l[s];
    offs[b*SEQ + s] = off_l[s];
  }
}

// ---------------- fused weight transpose-convert for all 10 weights ----------------
struct WtJob { const float* W[10]; bf16_t* WT[10]; };
__global__ __launch_bounds__(256) void k_wt_all(WtJob j){
  __shared__ float T[32][65];
  int t = blockIdx.x, k0 = blockIdx.y*32;
  int wsel, n0, N;
  if (t < 64){ wsel = t>>3; n0 = (t&7)*64; N = 512; }
  else { int t2 = t-64; wsel = 8 + (t2>>6); n0 = (t2&63)*64; N = 4096; }
  const float* W = j.W[wsel];
  bf16_t* WT = j.WT[wsel];
  const int K = 512;
  int tid = threadIdx.x;
  int lk = tid>>3, ln = (tid&7)*8;
  const float* src = W + (size_t)(k0+lk)*N + n0 + ln;
  float4 v0 = *(const float4*)src;
  float4 v1 = *(const float4*)(src+4);
  T[lk][ln+0]=v0.x; T[lk][ln+1]=v0.y; T[lk][ln+2]=v0.z; T[lk][ln+3]=v0.w;
  T[lk][ln+4]=v1.x; T[lk][ln+5]=v1.y; T[lk][ln+6]=v1.z; T[lk][ln+7]=v1.w;
  __syncthreads();
  int wn = tid>>2, wk = (tid&3)*8;
  ushort4 o0, o1;
  o0.x=f2bf(T[wk+0][wn]); o0.y=f2bf(T[wk+1][wn]); o0.z=f2bf(T[wk+2][wn]); o0.w=f2bf(T[wk+3][wn]);
  o1.x=f2bf(T[wk+4][wn]); o1.y=f2bf(T[wk+5][wn]); o1.z=f2bf(T[wk+6][wn]); o1.w=f2bf(T[wk+7][wn]);
  bf16_t* dst = WT + (size_t)(n0+wn)*K + k0 + wk;
  *(ushort4*)dst = o0;
  *(ushort4*)(dst+4) = o1;
}

// ---------------- MFMA GEMM: 64x64 tile, BK=64, LDS dbuf, scalar prefetch regs ----------------
struct GemmB {
  const bf16_t* W; const float* bias; float* C; bf16_t* Cb;
  const float* att_s; const float* att_d; float* asrc; float* adst;
};
struct GemmB3 { GemmB g[3]; };

__global__ __launch_bounds__(256) void k_gemm_mfma(const bf16_t* __restrict__ A, GemmB3 p,
                                                   int N, int K){
  const GemmB& g = p.g[blockIdx.z];
  const bf16_t* Wt  = g.W;
  const float* bias = g.bias;
  float* C          = g.C;
  bf16_t* Cb        = g.Cb;
  __shared__ __align__(16) bf16_t As[2][64*72];
  __shared__ __align__(16) bf16_t Bs[2][64*72];
  int bm = blockIdx.x*64, bn = blockIdx.y*64;
  int tid = threadIdx.x;
  int wave = tid>>6, lane = tid&63;
  int wy = wave>>1, wx = wave&1;
  int quad = lane>>4, l16 = lane&15;
  floatx4 acc[2][2];
  #pragma unroll
  for (int i=0;i<2;i++)
    #pragma unroll
    for (int j=0;j<2;j++) acc[i][j] = (floatx4){0.f,0.f,0.f,0.f};
  int sr = tid>>2;
  int sc = (tid&3)<<4;
  const bf16_t* Aptr = A  + (size_t)(bm+sr)*K + sc;
  const bf16_t* Bptr = Wt + (size_t)(bn+sr)*K + sc;
  uint4 a0, a1, b0, b1;
  a0 = *(const uint4*)(Aptr);     a1 = *(const uint4*)(Aptr + 8);
  b0 = *(const uint4*)(Bptr);     b1 = *(const uint4*)(Bptr + 8);
  *(uint4*)(As[0] + sr*72 + sc)     = a0;
  *(uint4*)(As[0] + sr*72 + sc + 8) = a1;
  *(uint4*)(Bs[0] + sr*72 + sc)     = b0;
  *(uint4*)(Bs[0] + sr*72 + sc + 8) = b1;
  const int nk = K>>6;
  for (int k=0; k<nk; k++){
    __syncthreads();
    if (k+1 < nk){
      int ko = (k+1)<<6;
      a0 = *(const uint4*)(Aptr + ko);     a1 = *(const uint4*)(Aptr + ko + 8);
      b0 = *(const uint4*)(Bptr + ko);     b1 = *(const uint4*)(Bptr + ko + 8);
    }
    const bf16_t* Ab = As[k&1];
    const bf16_t* Bb = Bs[k&1];
    short8 af[2][2], bfr[2][2];
    #pragma unroll
    for (int i=0;i<2;i++){
      af[0][i] = *(const short8*)(Ab + (wy*32+i*16+l16)*72 + quad*8);
      af[1][i] = *(const short8*)(Ab + (wy*32+i*16+l16)*72 + 32 + quad*8);
    }
    #pragma unroll
    for (int j=0;j<2;j++){
      bfr[0][j] = *(const short8*)(Bb + (wx*32+j*16+l16)*72 + quad*8);
      bfr[1][j] = *(const short8*)(Bb + (wx*32+j*16+l16)*72 + 32 + quad*8);
    }
    #pragma unroll
    for (int i=0;i<2;i++)
      #pragma unroll
      for (int j=0;j<2;j++){
        acc[i][j] = __builtin_amdgcn_mfma_f32_16x16x32_bf16(af[0][i], bfr[0][j], acc[i][j], 0,0,0);
        acc[i][j] = __builtin_amdgcn_mfma_f32_16x16x32_bf16(af[1][i], bfr[1][j], acc[i][j], 0,0,0);
      }
    if (k+1 < nk){
      bf16_t* Aw = As[(k+1)&1];
      bf16_t* Bw = Bs[(k+1)&1];
      *(uint4*)(Aw + sr*72 + sc)     = a0;
      *(uint4*)(Aw + sr*72 + sc + 8) = a1;
      *(uint4*)(Bw + sr*72 + sc)     = b0;
      *(uint4*)(Bw + sr*72 + sc + 8) = b1;
    }
  }
  #pragma unroll
  for (int i=0;i<2;i++){
    int row = bm + wy*32 + i*16 + quad*4;
    #pragma unroll
    for (int j=0;j<2;j++){
      int col = bn + wx*32 + j*16 + l16;
      float bi = bias ? bias[col] : 0.f;
      #pragma unroll
      for (int r=0;r<4;r++){
        float vvv = acc[i][j][r] + bi;
        if (C)  C[(size_t)(row+r)*N + col] = vvv;
        if (Cb) Cb[(size_t)(row+r)*N + col] = f2bf(vvv);
      }
    }
  }
  if (g.asrc){
    int colbase = bn + wx*32;
    int hidx = colbase >> 9;
    float aw_s[2], aw_d[2];
    #pragma unroll
    for (int j=0;j<2;j++){
      int col = colbase + j*16 + l16;
      aw_s[j] = g.att_s[col];
      aw_d[j] = g.att_d[col];
    }
    #pragma unroll
    for (int i=0;i<2;i++){
      #pragma unroll
      for (int r=0;r<4;r++){
        float ps=0.f, pd=0.f;
        #pragma unroll
        for (int j=0;j<2;j++){ ps += acc[i][j][r]*aw_s[j]; pd += acc[i][j][r]*aw_d[j]; }
        #pragma unroll
        for (int m2=1;m2<16;m2<<=1){ ps += __shfl_xor(ps,m2); pd += __shfl_xor(pd,m2); }
        if (l16==0){
          int row = bm + wy*32 + i*16 + quad*4 + r;
          atomicAdd(&g.asrc[row*HEADS + hidx], ps);
          atomicAdd(&g.adst[row*HEADS + hidx], pd);
        }
      }
    }
  }
}

// ---------------- flash MFMA attention: 64 queries/block, bf16 in/out ----------------
__global__ __launch_bounds__(256) void k_attn_flash(const bf16_t* __restrict__ q,
    const bf16_t* __restrict__ k, const bf16_t* __restrict__ v,
    const int* __restrict__ input_len, bf16_t* __restrict__ o){
  __shared__ __align__(16) bf16_t Kt[64*72];
  __shared__ __align__(16) bf16_t Vt[64*72];
  __shared__ __align__(16) bf16_t Pt[4][16*72];
  int q0 = blockIdx.x*64;
  int h  = blockIdx.y, b = blockIdx.z;
  int len = input_len[b];
  int tid = threadIdx.x;
  int w = tid>>6, lane = tid&63;
  int quad = lane>>4, l16 = lane&15;
  const bf16_t* qrow = q + ((size_t)(b*SEQ + q0 + w*16 + l16))*DMODEL + h*DH;
  short8 qa0 = *(const short8*)(qrow + quad*8);
  short8 qa1 = *(const short8*)(qrow + quad*8 + 32);
  int kr = tid>>2, kc = (tid&3)<<4;
  int vr = lane,   vc = w<<4;
  const bf16_t* kbase = k + ((size_t)(b*SEQ))*DMODEL + h*DH;
  const bf16_t* vbase = v + ((size_t)(b*SEQ))*DMODEL + h*DH;
  floatx4 oacc[4];
  #pragma unroll
  for (int dt=0;dt<4;dt++) oacc[dt] = (floatx4){0.f,0.f,0.f,0.f};
  float mrun[4], lrun[4];
  #pragma unroll
  for (int r=0;r<4;r++){ mrun[r]=-1e30f; lrun[r]=0.f; }
  for (int kt=0; kt<SEQ; kt+=64){
    if (kt >= len) break;
    uint4 kv0 = *(const uint4*)(kbase + (size_t)(kt+kr)*DMODEL + kc);
    uint4 kv1 = *(const uint4*)(kbase + (size_t)(kt+kr)*DMODEL + kc + 8);
    uint4 vv0 = *(const uint4*)(vbase + (size_t)(kt+vr)*DMODEL + vc);
    uint4 vv1 = *(const uint4*)(vbase + (size_t)(kt+vr)*DMODEL + vc + 8);
    __syncthreads();
    *(uint4*)(Kt + kr*72 + kc)     = kv0;
    *(uint4*)(Kt + kr*72 + kc + 8) = kv1;
    const ushort* vp0 = (const ushort*)&vv0;
    const ushort* vp1 = (const ushort*)&vv1;
    #pragma unroll
    for (int i2=0;i2<8;i2++) Vt[(vc+i2)*72 + vr]   = vp0[i2];
    #pragma unroll
    for (int i2=0;i2<8;i2++) Vt[(vc+8+i2)*72 + vr] = vp1[i2];
    __syncthreads();
    floatx4 sacc[4];
    #pragma unroll
    for (int nt=0;nt<4;nt++){
      sacc[nt] = (floatx4){0.f,0.f,0.f,0.f};
      short8 kb0 = *(const short8*)(Kt + (nt*16+l16)*72 + quad*8);
      short8 kb1 = *(const short8*)(Kt + (nt*16+l16)*72 + quad*8 + 32);
      sacc[nt] = __builtin_amdgcn_mfma_f32_16x16x32_bf16(qa0, kb0, sacc[nt], 0,0,0);
      sacc[nt] = __builtin_amdgcn_mfma_f32_16x16x32_bf16(qa1, kb1, sacc[nt], 0,0,0);
    }
    #pragma unroll
    for (int nt=0;nt<4;nt++){
      bool valid = (kt + nt*16 + l16) < len;
      #pragma unroll
      for (int r=0;r<4;r++){
        float sv = sacc[nt][r]*0.125f;
        sacc[nt][r] = valid ? sv : -1e30f;
      }
    }
    float alpha[4];
    #pragma unroll
    for (int r=0;r<4;r++){
      float mx = fmaxf(fmaxf(sacc[0][r],sacc[1][r]), fmaxf(sacc[2][r],sacc[3][r]));
      #pragma unroll
      for (int off=1; off<16; off<<=1) mx = fmaxf(mx, __shfl_xor(mx, off));
      float mn = fmaxf(mrun[r], mx);
      alpha[r] = __expf(mrun[r]-mn);
      mrun[r] = mn;
      float rs = 0.f;
      #pragma unroll
      for (int nt=0;nt<4;nt++){
        float pp = __expf(sacc[nt][r]-mn);
        sacc[nt][r] = pp; rs += pp;
      }
      #pragma unroll
      for (int off=1; off<16; off<<=1) rs += __shfl_xor(rs, off);
      lrun[r] = lrun[r]*alpha[r] + rs;
    }
    #pragma unroll
    for (int dt=0;dt<4;dt++)
      #pragma unroll
      for (int r=0;r<4;r++) oacc[dt][r] *= alpha[r];
    bf16_t* pw = Pt[w];
    #pragma unroll
    for (int nt=0;nt<4;nt++)
      #pragma unroll
      for (int r=0;r<4;r++) pw[(quad*4+r)*72 + nt*16 + l16] = f2bf(sacc[nt][r]);
    short8 pa0 = *(const short8*)(pw + l16*72 + quad*8);
    short8 pa1 = *(const short8*)(pw + l16*72 + quad*8 + 32);
    #pragma unroll
    for (int dt=0;dt<4;dt++){
      short8 vb0 = *(const short8*)(Vt + (dt*16+l16)*72 + quad*8);
      short8 vb1 = *(const short8*)(Vt + (dt*16+l16)*72 + quad*8 + 32);
      oacc[dt] = __builtin_amdgcn_mfma_f32_16x16x32_bf16(pa0, vb0, oacc[dt], 0,0,0);
      oacc[dt] = __builtin_amdgcn_mfma_f32_16x16x32_bf16(pa1, vb1, oacc[dt], 0,0,0);
    }
  }
  bf16_t* obase = o + ((size_t)(b*SEQ + q0 + w*16 + quad*4))*DMODEL + h*DH;
  #pragma unroll
  for (int r=0;r<4;r++){
    float invl = 1.f/lrun[r];
    #pragma unroll
    for (int dt=0;dt<4;dt++)
      obase[(size_t)r*DMODEL + dt*16 + l16] = f2bf(oacc[dt][r]*invl);
  }
}

// ---------------- fused GAT aggregation + LN + ReLU + residual + mask ----------------
// phase 1 (softmax max/denom) distributed over all 4 waves: wave w handles heads {2w, 2w+1}
__global__ __launch_bounds__(256) void k_gat_ln(const bf16_t* __restrict__ hbuf,
    const float* __restrict__ asrc, const float* __restrict__ adst,
    const int* __restrict__ offs, const int* __restrict__ cnt, const int* __restrict__ elist,
    const int* __restrict__ edges, const int* __restrict__ input_len,
    const float* __restrict__ gat_bias, const float* __restrict__ mha,
    const float* __restrict__ lng, const float* __restrict__ lnb,
    bf16_t* __restrict__ curb, float* __restrict__ outp){
  int s = blockIdx.x, b = blockIdx.y;
  int tid = threadIdx.x;
  size_t row = ((size_t)(b*SEQ+s))*DMODEL;
  int c0 = tid*2;
  float2 xv = *(const float2*)(mha + row + c0);
  if (s >= input_len[b]){
    curb[row+c0]   = f2bf(xv.x);
    curb[row+c0+1] = f2bf(xv.y);
    *(float2*)(outp + row + c0) = xv;
    return;
  }
  __shared__ float amax_s[8], den_s[8], adl[8];
  __shared__ float cf[32][8];
  __shared__ int   cs[32];
  __shared__ float red[256];
  int n = cnt[b*SEQ+s];
  const int* el = elist + (size_t)b*NEDGE + offs[b*SEQ+s];
  const int* srcrow = edges + (size_t)b*2*NEDGE;
  if (tid < 8) adl[tid] = adst[(b*SEQ+s)*HEADS + tid];
  __syncthreads();
  {
    int w = tid>>6, lane = tid&63;
    int h0 = w*2, h1 = h0+1;
    float ad0 = adl[h0], ad1 = adl[h1];
    float mx0 = -1e30f, mx1 = -1e30f;
    for (int j = lane; j <= n; j += 64){
      int src = (j==n) ? s : srcrow[el[j]];
      const float* ap = asrc + (size_t)(b*SEQ+src)*HEADS;
      float a0 = ap[h0] + ad0; a0 = (a0>0.f)? a0 : 0.2f*a0;
      float a1 = ap[h1] + ad1; a1 = (a1>0.f)? a1 : 0.2f*a1;
      mx0 = fmaxf(mx0, a0); mx1 = fmaxf(mx1, a1);
    }
    #pragma unroll
    for (int off=32; off; off>>=1){
      mx0 = fmaxf(mx0, __shfl_xor(mx0,off,64));
      mx1 = fmaxf(mx1, __shfl_xor(mx1,off,64));
    }
    float sm0 = 0.f, sm1 = 0.f;
    for (int j = lane; j <= n; j += 64){
      int src = (j==n) ? s : srcrow[el[j]];
      const float* ap = asrc + (size_t)(b*SEQ+src)*HEADS;
      float a0 = ap[h0] + ad0; a0 = (a0>0.f)? a0 : 0.2f*a0;
      float a1 = ap[h1] + ad1; a1 = (a1>0.f)? a1 : 0.2f*a1;
      sm0 += __expf(a0 - mx0); sm1 += __expf(a1 - mx1);
    }
    #pragma unroll
    for (int off=32; off; off>>=1){
      sm0 += __shfl_xor(sm0,off,64);
      sm1 += __shfl_xor(sm1,off,64);
    }
    if (lane==0){
      amax_s[h0]=mx0; den_s[h0]=sm0;
      amax_s[h1]=mx1; den_s[h1]=sm1;
    }
  }
  __syncthreads();
  float acc0=0.f, acc1=0.f;
  for (int j0=0; j0 <= n; j0 += 32){
    int jm = min(32, n+1-j0);
    if (tid < jm*8){
      int jj = j0 + (tid>>3), h2 = tid&7;
      int src = (jj==n) ? s : srcrow[el[jj]];
      if (h2==0) cs[tid>>3] = src;
      float a = asrc[(size_t)(b*SEQ+src)*HEADS + h2] + adl[h2];
      a = (a>0.f)? a : 0.2f*a;
      cf[tid>>3][h2] = __expf(a - amax_s[h2]) / (den_s[h2] + 1e-16f);
    }
    __syncthreads();
    for (int jj=0; jj<jm; ++jj){
      int src = cs[jj];
      const bf16_t* hrow = hbuf + ((size_t)(b*SEQ+src))*HC;
      #pragma unroll
      for (int h2=0;h2<8;h2++){
        float wgt = cf[jj][h2];
        ushort2 hv = *(const ushort2*)(hrow + h2*CCH + c0);
        acc0 += wgt * bf2f(hv.x);
        acc1 += wgt * bf2f(hv.y);
      }
    }
    __syncthreads();
  }
  float g0 = acc0*0.125f + gat_bias[c0];
  float g1 = acc1*0.125f + gat_bias[c0+1];
  red[tid] = g0+g1;
  __syncthreads();
  for (int off=128; off; off>>=1){ if (tid<off) red[tid]+=red[tid+off]; __syncthreads(); }
  float mean = red[0]*(1.f/512.f);
  __syncthreads();
  float d0 = g0-mean, d1 = g1-mean;
  red[tid] = d0*d0 + d1*d1;
  __syncthreads();
  for (int off=128; off; off>>=1){ if (tid<off) red[tid]+=red[tid+off]; __syncthreads(); }
  float inv = rsqrtf(red[0]*(1.f/512.f) + 1e-5f);
  float t0 = d0*inv*lng[c0]   + lnb[c0];
  float t1 = d1*inv*lng[c0+1] + lnb[c0+1];
  float y0 = fmaxf(t0,0.f) + xv.x;
  float y1 = fmaxf(t1,0.f) + xv.y;
  curb[row+c0]   = f2bf(y0);
  curb[row+c0+1] = f2bf(y1);
  float2 outv = { y0, y1 };
  *(float2*)(outp + row + c0) = outv;
}

extern "C" void kernel_launch(void* const* d_in, const int* in_sizes, int n_in,
                              void* d_out, int out_size, void* d_ws, size_t ws_size,
                              hipStream_t stream){
  (void)in_sizes; (void)n_in; (void)out_size; (void)ws_size;
  const float* x       = (const float*)d_in[0];
  const float* Wq      = (const float*)d_in[1];
  const float* bq      = (const float*)d_in[2];
  const float* Wk      = (const float*)d_in[3];
  const float* bk      = (const float*)d_in[4];
  const float* Wv      = (const float*)d_in[5];
  const float* bv      = (const float*)d_in[6];
  const float* Wo      = (const float*)d_in[7];
  const float* bo      = (const float*)d_in[8];
  const float* gatW    = (const float*)d_in[9];
  const float* att_src = (const float*)d_in[10];
  const float* att_dst = (const float*)d_in[11];
  const float* gat_bias= (const float*)d_in[12];
  const float* ln_g    = (const float*)d_in[13];
  const float* ln_b    = (const float*)d_in[14];
  const int* input_len  = (const int*)d_in[15];
  const int* edges      = (const int*)d_in[16];
  const int* edge_num   = (const int*)d_in[17];
  float* outp = (float*)d_out;

  char* w = (char*)d_ws;
  size_t off = 0;
  auto alloc = [&](size_t bytes)->char*{ char* p = w + off; off += (bytes + 255) & ~(size_t)255; return p; };
  const size_t BSD = (size_t)BATCH*SEQ*DMODEL;
  const size_t BSH = (size_t)BATCH*SEQ*HEADS;
  float* mha  = (float*)alloc(BSD*4);
  bf16_t* hb  = (bf16_t*)alloc((size_t)BATCH*SEQ*HC*2);
  float* attn_nodes = (float*)alloc((size_t)NLAYER*2*BSH*4);
  int* cnt    = (int*)alloc(BATCH*SEQ*4);
  int* offs   = (int*)alloc(BATCH*SEQ*4);
  int* elist  = (int*)alloc((size_t)BATCH*NEDGE*4);
  bf16_t* xbf  = (bf16_t*)alloc(BSD*2);
  bf16_t* curb = (bf16_t*)alloc(BSD*2);
  bf16_t* qbf  = (bf16_t*)alloc(BSD*2);
  bf16_t* kbf  = (bf16_t*)alloc(BSD*2);
  bf16_t* vbf  = (bf16_t*)alloc(BSD*2);
  bf16_t* obf  = (bf16_t*)alloc(BSD*2);
  bf16_t* abf  = (bf16_t*)alloc(BSD*2);
  bf16_t* wqt  = (bf16_t*)alloc((size_t)NLAYER*DMODEL*DMODEL*2);
  bf16_t* wkt  = (bf16_t*)alloc((size_t)NLAYER*DMODEL*DMODEL*2);
  bf16_t* wvt  = (bf16_t*)alloc((size_t)NLAYER*DMODEL*DMODEL*2);
  bf16_t* wot  = (bf16_t*)alloc((size_t)NLAYER*DMODEL*DMODEL*2);
  bf16_t* gwt  = (bf16_t*)alloc((size_t)NLAYER*DMODEL*HC*2);

  k_edges<<<dim3(BATCH),256,0,stream>>>(edges, edge_num, cnt, offs, elist,
                                        attn_nodes, (int)(NLAYER*2*BSH));
  WtJob wj;
  for (int i=0;i<NLAYER;i++){
    size_t wo = (size_t)i*DMODEL*DMODEL;
    wj.W[i*4+0]=Wq+wo;  wj.WT[i*4+0]=wqt+wo;
    wj.W[i*4+1]=Wk+wo;  wj.WT[i*4+1]=wkt+wo;
    wj.W[i*4+2]=Wv+wo;  wj.WT[i*4+2]=wvt+wo;
    wj.W[i*4+3]=Wo+wo;  wj.WT[i*4+3]=wot+wo;
    size_t go = (size_t)i*DMODEL*HC;
    wj.W[8+i]=gatW+go;  wj.WT[8+i]=gwt+go;
  }
  k_wt_all<<<dim3(192, 16),256,0,stream>>>(wj);
  k_f2b<<<dim3((unsigned)(BSD/4/256)),256,0,stream>>>(x, xbf, (int)(BSD/4));

  const int M = BATCH*SEQ;
  for (int i=0;i<NLAYER;i++){
    size_t wo = (size_t)i*DMODEL*DMODEL;
    size_t bo2 = (size_t)i*DMODEL;
    float* asrc = attn_nodes + (size_t)i*2*BSH;
    float* adst = asrc + BSH;
    const bf16_t* Ab = (i==0) ? xbf : curb;
    GemmB3 qkv;
    qkv.g[0] = { wqt+wo, bq+bo2, nullptr, qbf, nullptr, nullptr, nullptr, nullptr };
    qkv.g[1] = { wkt+wo, bk+bo2, nullptr, kbf, nullptr, nullptr, nullptr, nullptr };
    qkv.g[2] = { wvt+wo, bv+bo2, nullptr, vbf, nullptr, nullptr, nullptr, nullptr };
    k_gemm_mfma<<<dim3(M/64, DMODEL/64, 3),256,0,stream>>>(Ab, qkv, DMODEL, DMODEL);
    k_attn_flash<<<dim3(SEQ/64, HEADS, BATCH),256,0,stream>>>(qbf, kbf, vbf, input_len, obf);
    GemmB3 og;
    og.g[0] = { wot+wo, bo+bo2, mha, abf, nullptr, nullptr, nullptr, nullptr };
    og.g[1] = og.g[0]; og.g[2] = og.g[0];
    k_gemm_mfma<<<dim3(M/64, DMODEL/64, 1),256,0,stream>>>(obf, og, DMODEL, DMODEL);
    GemmB3 gg;
    gg.g[0] = { gwt + (size_t)i*DMODEL*HC, nullptr, nullptr, hb,
                att_src + (size_t)i*HC, att_dst + (size_t)i*HC, asrc, adst };
    gg.g[1] = gg.g[0]; gg.g[2] = gg.g[0];
    k_gemm_mfma<<<dim3(M/64, HC/64, 1),256,0,stream>>>(abf, gg, HC, DMODEL);
    k_gat_ln<<<dim3(SEQ, BATCH),256,0,stream>>>(hb, asrc, adst, offs, cnt, elist, edges,
        input_len, gat_bias + (size_t)i*CCH, mha, ln_g+bo2, ln_b+bo2,
        curb, outp + (size_t)i*BSD);
  }
}